// Round 1
// baseline (576.699 us; speedup 1.0000x reference)
//
#include <hip/hip_runtime.h>
#include <hip/hip_bf16.h>
#include <stdint.h>

#define DIM   2048
#define NSLOT 64
#define MDIM  512
#define TINV  10.0f   // 1/TEMP
#define RPB   8       // rows per block in fused kernel

// ---------------------------------------------------------------------------
// ws layout (floats):
//   W2T [2048][64]  : W2T[k][n] = sum_m memory[n][m]*key_w[m][k]   (512 KB)
//   W3  [64][2048]  : W3[n][d]  = sum_m memory[n][m]*value_w[d][m] (512 KB)
//   h   [64]        : h[n]      = sum_d W3[n][d]*gate_w[DIM+d]
// ---------------------------------------------------------------------------

__global__ __launch_bounds__(256) void prep_kernel(
    const float* __restrict__ memory,   // [64][512]
    const float* __restrict__ key_w,    // [512][2048]
    const float* __restrict__ value_w,  // [2048][512]
    float* __restrict__ W2T,            // [2048][64]
    float* __restrict__ W3)             // [64][2048]
{
    __shared__ __align__(16) float mem_s[8 * MDIM];
    const int tid = threadIdx.x;
    const int c = blockIdx.x;   // 0..7 : 256-wide chunk over k (and d)
    const int g = blockIdx.y;   // 0..7 : group of 8 slots

    for (int i = tid; i < 8 * MDIM; i += 256)
        mem_s[i] = memory[g * 8 * MDIM + i];
    __syncthreads();

    const float4* ms4 = (const float4*)mem_s;

    // ---- W2T: k = c*256 + tid ----
    {
        const int k = c * 256 + tid;
        float acc[8] = {};
        for (int m4 = 0; m4 < MDIM / 4; ++m4) {
            const float kw0 = key_w[(size_t)(m4 * 4 + 0) * DIM + k];
            const float kw1 = key_w[(size_t)(m4 * 4 + 1) * DIM + k];
            const float kw2 = key_w[(size_t)(m4 * 4 + 2) * DIM + k];
            const float kw3 = key_w[(size_t)(m4 * 4 + 3) * DIM + k];
            #pragma unroll
            for (int i = 0; i < 8; ++i) {
                const float4 mv = ms4[i * (MDIM / 4) + m4];
                acc[i] = fmaf(mv.x, kw0, acc[i]);
                acc[i] = fmaf(mv.y, kw1, acc[i]);
                acc[i] = fmaf(mv.z, kw2, acc[i]);
                acc[i] = fmaf(mv.w, kw3, acc[i]);
            }
        }
        #pragma unroll
        for (int i = 0; i < 8; ++i)
            W2T[(size_t)k * NSLOT + g * 8 + i] = acc[i];
    }

    // ---- W3: d = c*256 + tid ----
    {
        const int d = c * 256 + tid;
        float acc[8] = {};
        const float4* vp = (const float4*)(value_w + (size_t)d * MDIM);
        for (int m4 = 0; m4 < MDIM / 4; ++m4) {
            const float4 v = vp[m4];
            #pragma unroll
            for (int i = 0; i < 8; ++i) {
                const float4 mv = ms4[i * (MDIM / 4) + m4];
                acc[i] = fmaf(mv.x, v.x, acc[i]);
                acc[i] = fmaf(mv.y, v.y, acc[i]);
                acc[i] = fmaf(mv.z, v.z, acc[i]);
                acc[i] = fmaf(mv.w, v.w, acc[i]);
            }
        }
        #pragma unroll
        for (int i = 0; i < 8; ++i)
            W3[(size_t)(g * 8 + i) * DIM + d] = acc[i];
    }
}

__global__ __launch_bounds__(512) void hvec_kernel(
    const float* __restrict__ W3,       // [64][2048]
    const float* __restrict__ gate_w,   // [4096]
    float* __restrict__ h)              // [64]
{
    const int lane = threadIdx.x & 63;
    const int w = threadIdx.x >> 6;     // 0..7
    #pragma unroll
    for (int q = 0; q < 8; ++q) {
        const int n = w * 8 + q;
        float p = 0.f;
        for (int j = lane; j < DIM; j += 64)
            p = fmaf(W3[(size_t)n * DIM + j], gate_w[DIM + j], p);
        #pragma unroll
        for (int off = 32; off; off >>= 1) p += __shfl_xor(p, off);
        if (lane == 0) h[n] = p;
    }
}

__global__ __launch_bounds__(512) void fused_kernel(
    const float* __restrict__ x,        // [32768][2048]
    const float* __restrict__ W2T,      // [2048][64]
    const float* __restrict__ W3,       // [64][2048]
    const float* __restrict__ h,        // [64]
    const float* __restrict__ gate_w,   // [4096]
    const float* __restrict__ gate_b,   // [1]
    float* __restrict__ out)            // [32768][2048]
{
    __shared__ float sc_part[8][RPB][NSLOT];  // [k-slice][row][slot] 16 KB
    __shared__ float attn_s[RPB][NSLOT];      // 2 KB
    __shared__ float gate_s[RPB];

    const int tid  = threadIdx.x;
    const int lane = tid & 63;
    const int w    = __builtin_amdgcn_readfirstlane(tid >> 6);  // wave id 0..7
    const size_t row0 = (size_t)blockIdx.x * RPB;

    // ---- phase 1: partial scores. wave w covers k in [w*256, w*256+256),
    //      all 8 rows; lane <-> slot n. W2T read exactly once per block. ----
    float acc[RPB] = {};
    {
        const int kbase = w * 256;
        const float* W2p = W2T + (size_t)kbase * NSLOT + lane;
        for (int kk = 0; kk < 256; kk += 8) {
            float wv[8];
            #pragma unroll
            for (int u = 0; u < 8; ++u) wv[u] = W2p[(size_t)(kk + u) * NSLOT];
            #pragma unroll
            for (int r = 0; r < RPB; ++r) {
                const float4* xp = (const float4*)(x + (row0 + r) * DIM + kbase + kk);
                const float4 xa = xp[0];
                const float4 xb = xp[1];
                acc[r] = fmaf(xa.x, wv[0], acc[r]);
                acc[r] = fmaf(xa.y, wv[1], acc[r]);
                acc[r] = fmaf(xa.z, wv[2], acc[r]);
                acc[r] = fmaf(xa.w, wv[3], acc[r]);
                acc[r] = fmaf(xb.x, wv[4], acc[r]);
                acc[r] = fmaf(xb.y, wv[5], acc[r]);
                acc[r] = fmaf(xb.z, wv[6], acc[r]);
                acc[r] = fmaf(xb.w, wv[7], acc[r]);
            }
        }
    }
    #pragma unroll
    for (int r = 0; r < RPB; ++r) sc_part[w][r][lane] = acc[r];
    __syncthreads();

    // ---- phase 2: combine + softmax. wave w owns row w; lane <-> slot. ----
    float s = 0.f;
    #pragma unroll
    for (int q = 0; q < 8; ++q) s += sc_part[q][w][lane];
    s *= TINV;
    float mx = s;
    #pragma unroll
    for (int off = 32; off; off >>= 1) mx = fmaxf(mx, __shfl_xor(mx, off));
    const float p = __expf(s - mx);
    float sum = p;
    #pragma unroll
    for (int off = 32; off; off >>= 1) sum += __shfl_xor(sum, off);
    const float a = p / sum;
    attn_s[w][lane] = a;

    // ---- phase 3: gate for row w. Folded: sum_d retr*g2 = sum_n attn*h. ----
    float gp = a * h[lane];
    {
        const float* xr = x + (row0 + w) * DIM;
        #pragma unroll 4
        for (int j = lane; j < DIM; j += 64)
            gp = fmaf(xr[j], gate_w[j], gp);
    }
    #pragma unroll
    for (int off = 32; off; off >>= 1) gp += __shfl_xor(gp, off);
    const float gate = 1.f / (1.f + __expf(-(gp + gate_b[0])));
    if (lane == 0) gate_s[w] = gate;
    __syncthreads();

    // ---- phase 5: retrieve + mix. Each thread owns d-chunk [tid*4, tid*4+4)
    //      for ALL 8 rows, so W3 is read exactly once per block. ----
    {
        float4 r4[RPB];
        #pragma unroll
        for (int r = 0; r < RPB; ++r) r4[r] = make_float4(0.f, 0.f, 0.f, 0.f);

        const float4* w3p = (const float4*)W3 + tid;   // element W3[n*2048 + tid*4]
        for (int n = 0; n < NSLOT; ++n) {
            const float4 wv = w3p[(size_t)n * (DIM / 4)];
            #pragma unroll
            for (int r = 0; r < RPB; ++r) {
                const float an = attn_s[r][n];
                r4[r].x = fmaf(an, wv.x, r4[r].x);
                r4[r].y = fmaf(an, wv.y, r4[r].y);
                r4[r].z = fmaf(an, wv.z, r4[r].z);
                r4[r].w = fmaf(an, wv.w, r4[r].w);
            }
        }

        #pragma unroll
        for (int r = 0; r < RPB; ++r) {
            const float g = gate_s[r];
            const float4 xv = *(const float4*)(x + (row0 + r) * DIM + tid * 4);
            float4 o;
            o.x = fmaf(g, xv.x - r4[r].x, r4[r].x);
            o.y = fmaf(g, xv.y - r4[r].y, r4[r].y);
            o.z = fmaf(g, xv.z - r4[r].z, r4[r].z);
            o.w = fmaf(g, xv.w - r4[r].w, r4[r].w);
            *(float4*)(out + (row0 + r) * DIM + tid * 4) = o;
        }
    }
}

extern "C" void kernel_launch(void* const* d_in, const int* in_sizes, int n_in,
                              void* d_out, int out_size, void* d_ws, size_t ws_size,
                              hipStream_t stream) {
    const float* x       = (const float*)d_in[0];
    const float* memory  = (const float*)d_in[1];
    const float* key_w   = (const float*)d_in[2];
    const float* value_w = (const float*)d_in[3];
    const float* gate_w  = (const float*)d_in[4];
    const float* gate_b  = (const float*)d_in[5];
    float* out = (float*)d_out;

    float* W2T = (float*)d_ws;                    // 2048*64 floats
    float* W3  = W2T + (size_t)DIM * NSLOT;       // 64*2048 floats
    float* h   = W3 + (size_t)NSLOT * DIM;        // 64 floats

    prep_kernel<<<dim3(8, 8), 256, 0, stream>>>(memory, key_w, value_w, W2T, W3);
    hvec_kernel<<<1, 512, 0, stream>>>(W3, gate_w, h);

    const int rows = 8 * 4096;
    fused_kernel<<<rows / RPB, 512, 0, stream>>>(x, W2T, W3, h, gate_w, gate_b, out);
}

// Round 2
// 335.701 us; speedup vs baseline: 1.7179x; 1.7179x over previous
//
#include <hip/hip_runtime.h>
#include <stdint.h>

#define DIM   2048
#define NSLOT 64
#define MDIM  512
#define TINV  10.0f

typedef __attribute__((ext_vector_type(4))) float     f32x4;
typedef __attribute__((ext_vector_type(8))) _Float16  half8;
typedef __attribute__((ext_vector_type(4))) unsigned int u32x4;

#define MFMA16(a,b,c) __builtin_amdgcn_mfma_f32_16x16x32_f16((a),(b),(c),0,0,0)

// ---------------------------------------------------------------------------
// ws layout (bytes), total ~5.26 MB:
//   W2h  [80][2048] f16 : rows 0-63 = memory@key_w, row 64 = gate_w[:2048], 65-79 = 0
//   W2l  [80][2048] f16 : fp16 residual of the above (2-way split)
//   W3T  [2048][64] f16 : W3T[d][n] = sum_m memory[n][m]*value_w[d][m]
//   h    [64] f32       : h[n] = sum_d W3[n][d]*gate_w[DIM+d]
//   tpart[8][512] f32   : partials for t[m] = sum_d value_w[d][m]*g2[d]
//   attn [32768][64] f16
//   gate [32768] f32
// ---------------------------------------------------------------------------
#define OFF_W2H   0
#define OFF_W2L   327680
#define OFF_W3T   655360
#define OFF_H     917504
#define OFF_TPART 917760
#define OFF_ATTN  934144
#define OFF_GATE  5128448

// ============================ prep kernels =================================

__global__ __launch_bounds__(256) void prep_w2(
    const float* __restrict__ memory, const float* __restrict__ key_w,
    const float* __restrict__ gate_w, _Float16* __restrict__ W2h,
    _Float16* __restrict__ W2l)
{
    const int tid = threadIdx.x;
    const int c = blockIdx.x;      // k-chunk of 256
    const int g = blockIdx.y;      // 0..7 slot groups, 8 = gate row + zero rows
    const int k = c * 256 + tid;

    if (g == 8) {
        float v = gate_w[k];
        _Float16 ph = (_Float16)v;
        _Float16 pl = (_Float16)(v - (float)ph);
        W2h[(size_t)64 * DIM + k] = ph;
        W2l[(size_t)64 * DIM + k] = pl;
        for (int r = 65; r < 80; ++r) {
            W2h[(size_t)r * DIM + k] = (_Float16)0.f;
            W2l[(size_t)r * DIM + k] = (_Float16)0.f;
        }
        return;
    }

    __shared__ __align__(16) float mem_s[8 * MDIM];
    for (int i = tid; i < 8 * MDIM; i += 256)
        mem_s[i] = memory[g * 8 * MDIM + i];
    __syncthreads();

    const f32x4* ms4 = (const f32x4*)mem_s;
    float acc[8] = {};
    for (int m4 = 0; m4 < MDIM / 4; ++m4) {
        const float kw0 = key_w[(size_t)(m4 * 4 + 0) * DIM + k];
        const float kw1 = key_w[(size_t)(m4 * 4 + 1) * DIM + k];
        const float kw2 = key_w[(size_t)(m4 * 4 + 2) * DIM + k];
        const float kw3 = key_w[(size_t)(m4 * 4 + 3) * DIM + k];
        #pragma unroll
        for (int i = 0; i < 8; ++i) {
            const f32x4 mv = ms4[i * (MDIM / 4) + m4];
            acc[i] = fmaf(mv.x, kw0, acc[i]);
            acc[i] = fmaf(mv.y, kw1, acc[i]);
            acc[i] = fmaf(mv.z, kw2, acc[i]);
            acc[i] = fmaf(mv.w, kw3, acc[i]);
        }
    }
    #pragma unroll
    for (int i = 0; i < 8; ++i) {
        float v = acc[i];
        _Float16 ph = (_Float16)v;
        _Float16 pl = (_Float16)(v - (float)ph);
        W2h[(size_t)(g * 8 + i) * DIM + k] = ph;
        W2l[(size_t)(g * 8 + i) * DIM + k] = pl;
    }
}

__global__ __launch_bounds__(256) void prep_w3t(
    const float* __restrict__ memory, const float* __restrict__ value_w,
    _Float16* __restrict__ W3T)
{
    const int tid = threadIdx.x;
    const int c = blockIdx.x;      // d-chunk of 256
    const int g = blockIdx.y;      // slot group of 8
    const int d = c * 256 + tid;

    __shared__ __align__(16) float mem_s[8 * MDIM];
    for (int i = tid; i < 8 * MDIM; i += 256)
        mem_s[i] = memory[g * 8 * MDIM + i];
    __syncthreads();

    const f32x4* ms4 = (const f32x4*)mem_s;
    const f32x4* vp = (const f32x4*)(value_w + (size_t)d * MDIM);
    float acc[8] = {};
    for (int m4 = 0; m4 < MDIM / 4; ++m4) {
        const f32x4 v = vp[m4];
        #pragma unroll
        for (int i = 0; i < 8; ++i) {
            const f32x4 mv = ms4[i * (MDIM / 4) + m4];
            acc[i] = fmaf(mv.x, v.x, acc[i]);
            acc[i] = fmaf(mv.y, v.y, acc[i]);
            acc[i] = fmaf(mv.z, v.z, acc[i]);
            acc[i] = fmaf(mv.w, v.w, acc[i]);
        }
    }
    #pragma unroll
    for (int i = 0; i < 8; ++i)
        W3T[(size_t)d * NSLOT + g * 8 + i] = (_Float16)acc[i];
}

__global__ __launch_bounds__(256) void prep_t(
    const float* __restrict__ value_w, const float* __restrict__ gate_w,
    float* __restrict__ tpart)
{
    const int b = blockIdx.x;      // d-chunk of 256
    const int tid = threadIdx.x;
    float a0 = 0.f, a1 = 0.f;
    for (int d = b * 256; d < b * 256 + 256; ++d) {
        const float gv = gate_w[DIM + d];
        a0 = fmaf(value_w[(size_t)d * MDIM + tid], gv, a0);
        a1 = fmaf(value_w[(size_t)d * MDIM + tid + 256], gv, a1);
    }
    tpart[b * 512 + tid] = a0;
    tpart[b * 512 + tid + 256] = a1;
}

__global__ __launch_bounds__(512) void prep_h(
    const float* __restrict__ memory, const float* __restrict__ tpart,
    float* __restrict__ h)
{
    __shared__ float ts[512];
    const int tid = threadIdx.x;
    float s = 0.f;
    #pragma unroll
    for (int b = 0; b < 8; ++b) s += tpart[b * 512 + tid];
    ts[tid] = s;
    __syncthreads();
    const int lane = tid & 63, w = tid >> 6;
    #pragma unroll
    for (int q = 0; q < 8; ++q) {
        const int n = w * 8 + q;
        float p = 0.f;
        for (int m = lane; m < MDIM; m += 64)
            p = fmaf(memory[(size_t)n * MDIM + m], ts[m], p);
        #pragma unroll
        for (int off = 32; off; off >>= 1) p += __shfl_xor(p, off);
        if (lane == 0) h[n] = p;
    }
}

// ============================ scores kernel ================================
// 64 rows/block, 4 waves; wave w owns m-tile w (16 rows), full K.
// 5 MFMA n-tiles: slots 0-63 + extended cols (64 = gate g1-dot, 65-79 zero).
// W2 chunks (128 k, hi+lo fp16) staged in LDS with XOR granule swizzle.
// x A-fragments loaded direct from global to regs, 2-way fp16 split in regs.
// In-register softmax + gate; writes attn fp16 + gate fp32.

__global__ __launch_bounds__(256) void scores_kernel(
    const float* __restrict__ x,
    const _Float16* __restrict__ W2h, const _Float16* __restrict__ W2l,
    const float* __restrict__ h, const float* __restrict__ gate_b,
    _Float16* __restrict__ attn_out, float* __restrict__ gate_out)
{
    __shared__ __align__(16) _Float16 w2s[2 * 80 * 128];   // 40 KB

    const int tid  = threadIdx.x;
    const int lane = tid & 63;
    const int w    = tid >> 6;          // wave = m-tile 0..3
    const int arow = lane & 15;         // A-row / B-row (lane&15)
    const int kg   = lane >> 4;         // k-group
    const size_t row0 = (size_t)blockIdx.x * 64;

    f32x4 acc[5];
    {   f32x4 z = {0.f, 0.f, 0.f, 0.f};
        #pragma unroll
        for (int t = 0; t < 5; ++t) acc[t] = z; }

    const float* xrow = x + (row0 + w * 16 + arow) * DIM + kg * 8;

    for (int ch = 0; ch < 16; ++ch) {
        // ---- stage W2 chunk (hi+lo) into LDS, swizzled dest ----
        u32x4 wg[10];
        #pragma unroll
        for (int i = 0; i < 10; ++i) {
            const int lvl = (i >= 5) ? 1 : 0;             // uniform per unrolled i
            const int gg = tid + i * 256 - lvl * 1280;    // granule within level
            const int rr = gg >> 4, gk = gg & 15;
            const _Float16* src = (lvl ? W2l : W2h) + (size_t)rr * DIM + ch * 128 + gk * 8;
            wg[i] = *(const u32x4*)src;
        }
        __syncthreads();   // previous chunk fully consumed
        #pragma unroll
        for (int i = 0; i < 10; ++i) {
            const int lvl = (i >= 5) ? 1 : 0;
            const int gg = tid + i * 256 - lvl * 1280;
            const int rr = gg >> 4, gk = gg & 15;
            *(u32x4*)(w2s + lvl * 10240 + rr * 128 + ((gk ^ (rr & 7)) * 8)) = wg[i];
        }
        __syncthreads();

        // ---- 4 k-steps of MFMA ----
        const int s = arow & 7;
        #pragma unroll
        for (int ks = 0; ks < 4; ++ks) {
            const f32x4 xa = *(const f32x4*)(xrow + ch * 128 + ks * 32);
            const f32x4 xb = *(const f32x4*)(xrow + ch * 128 + ks * 32 + 4);
            const float xf[8] = {xa.x, xa.y, xa.z, xa.w, xb.x, xb.y, xb.z, xb.w};
            _Float16 hh[8], ll[8];
            #pragma unroll
            for (int u = 0; u < 8; ++u) {
                hh[u] = (_Float16)xf[u];
                ll[u] = (_Float16)(xf[u] - (float)hh[u]);
            }
            const half8 ah = {hh[0], hh[1], hh[2], hh[3], hh[4], hh[5], hh[6], hh[7]};
            const half8 al = {ll[0], ll[1], ll[2], ll[3], ll[4], ll[5], ll[6], ll[7]};
            const int Gb = ks * 4 + kg;
            #pragma unroll
            for (int t = 0; t < 5; ++t) {
                const _Float16* bp = w2s + (t * 16 + arow) * 128 + ((Gb ^ s) * 8);
                const half8 bh = *(const half8*)bp;
                const half8 bl = *(const half8*)(bp + 10240);
                acc[t] = MFMA16(ah, bh, acc[t]);
                acc[t] = MFMA16(al, bh, acc[t]);
                acc[t] = MFMA16(ah, bl, acc[t]);
            }
        }
    }

    // ---- in-register softmax + gate ----
    // D layout: value = score[row = kg*4 + j][col = t*16 + arow]
    float hl[4];
    #pragma unroll
    for (int t = 0; t < 4; ++t) hl[t] = h[t * 16 + arow];
    const float gb = gate_b[0];

    #pragma unroll
    for (int j = 0; j < 4; ++j) {
        float m = fmaxf(fmaxf(acc[0][j], acc[1][j]), fmaxf(acc[2][j], acc[3][j]));
        #pragma unroll
        for (int off = 1; off < 16; off <<= 1) m = fmaxf(m, __shfl_xor(m, off));
        float p[4];
        float sum = 0.f;
        #pragma unroll
        for (int t = 0; t < 4; ++t) { p[t] = __expf((acc[t][j] - m) * TINV); sum += p[t]; }
        #pragma unroll
        for (int off = 1; off < 16; off <<= 1) sum += __shfl_xor(sum, off);
        const float inv = 1.f / sum;
        const size_t row = row0 + w * 16 + kg * 4 + j;
        float gp = 0.f;
        #pragma unroll
        for (int t = 0; t < 4; ++t) {
            const float a = p[t] * inv;
            attn_out[row * NSLOT + t * 16 + arow] = (_Float16)a;
            gp = fmaf(a, hl[t], gp);
        }
        #pragma unroll
        for (int off = 1; off < 16; off <<= 1) gp += __shfl_xor(gp, off);
        const float sg = __shfl(acc[4][j], lane & 48);   // gate col (raw, no TINV)
        if (arow == 0)
            gate_out[row] = 1.f / (1.f + __expf(-(sg + gp + gb)));
    }
}

// =========================== retrieve kernel ===============================
// 64 rows/block, 8 waves: wave = (m-tile = w>>1, d-half = w&1).
// retrieved = attn(fp16) @ W3 via MFMA (K=64 -> 2 steps); acc transposed
// through padded LDS tile; fused gate-mix; coalesced float4 out.

__global__ __launch_bounds__(512) void retrieve_kernel(
    const float* __restrict__ x, const _Float16* __restrict__ attn,
    const _Float16* __restrict__ W3T, const float* __restrict__ gate_arr,
    float* __restrict__ out)
{
    __shared__ float stag[8][2][16][17];

    const int tid  = threadIdx.x;
    const int lane = tid & 63;
    const int w    = tid >> 6;
    const int arow = lane & 15;
    const int kg   = lane >> 4;
    const int mt   = w >> 1;
    const int dh   = w & 1;
    const size_t rbase = (size_t)blockIdx.x * 64 + mt * 16;

    const _Float16* ap = attn + (rbase + arow) * NSLOT + kg * 8;
    const half8 a0 = *(const half8*)ap;
    const half8 a1 = *(const half8*)(ap + 32);
    const float g = gate_arr[rbase + arow];

    #pragma unroll 2
    for (int nt = 0; nt < 64; ++nt) {
        const int buf = nt & 1;
        const int d0 = dh * 1024 + nt * 16;
        const _Float16* bp = W3T + (size_t)(d0 + arow) * NSLOT + kg * 8;
        const half8 b0 = *(const half8*)bp;
        const half8 b1 = *(const half8*)(bp + 32);
        f32x4 acc = {0.f, 0.f, 0.f, 0.f};
        acc = MFMA16(a0, b0, acc);
        acc = MFMA16(a1, b1, acc);
        // transpose: stag[attn_row][d_col]
        #pragma unroll
        for (int r = 0; r < 4; ++r) stag[w][buf][kg * 4 + r][arow] = acc[r];
        float rv[4];
        #pragma unroll
        for (int i = 0; i < 4; ++i) rv[i] = stag[w][buf][arow][kg * 4 + i];
        const size_t base = (rbase + arow) * DIM + d0 + kg * 4;
        const f32x4 xv = *(const f32x4*)(x + base);
        f32x4 o;
        o.x = fmaf(g, xv.x - rv[0], rv[0]);
        o.y = fmaf(g, xv.y - rv[1], rv[1]);
        o.z = fmaf(g, xv.z - rv[2], rv[2]);
        o.w = fmaf(g, xv.w - rv[3], rv[3]);
        *(f32x4*)(out + base) = o;
    }
}

// ================================ launch ===================================

extern "C" void kernel_launch(void* const* d_in, const int* in_sizes, int n_in,
                              void* d_out, int out_size, void* d_ws, size_t ws_size,
                              hipStream_t stream) {
    (void)in_sizes; (void)n_in; (void)out_size; (void)ws_size;
    const float* x       = (const float*)d_in[0];
    const float* memory  = (const float*)d_in[1];
    const float* key_w   = (const float*)d_in[2];
    const float* value_w = (const float*)d_in[3];
    const float* gate_w  = (const float*)d_in[4];
    const float* gate_b  = (const float*)d_in[5];
    float* out = (float*)d_out;

    char* wsb = (char*)d_ws;                       // needs ~5.3 MB
    _Float16* W2h  = (_Float16*)(wsb + OFF_W2H);
    _Float16* W2l  = (_Float16*)(wsb + OFF_W2L);
    _Float16* W3T  = (_Float16*)(wsb + OFF_W3T);
    float*    h    = (float*)(wsb + OFF_H);
    float*    tpt  = (float*)(wsb + OFF_TPART);
    _Float16* attn = (_Float16*)(wsb + OFF_ATTN);
    float*    gate = (float*)(wsb + OFF_GATE);

    prep_w2 <<<dim3(8, 9), 256, 0, stream>>>(memory, key_w, gate_w, W2h, W2l);
    prep_w3t<<<dim3(8, 8), 256, 0, stream>>>(memory, value_w, W3T);
    prep_t  <<<8, 256, 0, stream>>>(value_w, gate_w, tpt);
    prep_h  <<<1, 512, 0, stream>>>(memory, tpt, h);

    scores_kernel  <<<512, 256, 0, stream>>>(x, W2h, W2l, h, gate_b, attn, gate);
    retrieve_kernel<<<512, 512, 0, stream>>>(x, attn, W3T, gate, out);
}